// Round 1
// baseline (262.757 us; speedup 1.0000x reference)
//
#include <hip/hip_runtime.h>
#include <math.h>

#define HH 256
#define WW 256
#define NG 1024
#define CF 15

// ---------------------------------------------------------------------------
// Kernel A: per-gaussian geometry + bitonic depth sort + write sorted SoA.
// One block of 1024 threads (one thread per gaussian).
// ws layout (float4 units): g0[NG] = {ux, uy, hA, hB}
//                           g1[NG] = {hC, op, pthr, 0}
//                           feat[NG*4] = 16 channels (15 feats + 1.0)
// ---------------------------------------------------------------------------
extern "C" __global__ __launch_bounds__(1024)
void geom_sort_kernel(const float* __restrict__ xyz,
                      const float* __restrict__ feats,
                      const float* __restrict__ opac,
                      const float* __restrict__ cov,
                      const float* __restrict__ Kp,
                      const float* __restrict__ Ep,
                      float4* __restrict__ g0,
                      float4* __restrict__ g1,
                      float4* __restrict__ feat_s)
{
    __shared__ float sg[8][NG];   // 32 KB
    __shared__ float skey[NG];    // 4 KB
    __shared__ int   sidx[NG];    // 4 KB

    const int i = threadIdx.x;

    const float fx = Kp[0], px = Kp[2], fy = Kp[4], py = Kp[5];
    const float R00 = Ep[0], R01 = Ep[1], R02 = Ep[2],  tr0 = Ep[3];
    const float R10 = Ep[4], R11 = Ep[5], R12 = Ep[6],  tr1 = Ep[7];
    const float R20 = Ep[8], R21 = Ep[9], R22 = Ep[10], tr2 = Ep[11];

    const float p0 = xyz[i * 3 + 0], p1 = xyz[i * 3 + 1], p2 = xyz[i * 3 + 2];
    const float t0 = R00 * p0 + R01 * p1 + R02 * p2 + tr0;
    const float t1 = R10 * p0 + R11 * p1 + R12 * p2 + tr1;
    const float tz = R20 * p0 + R21 * p1 + R22 * p2 + tr2;

    const float limx = 1.3f * ((float)WW / (2.0f * fx));
    const float limy = 1.3f * ((float)HH / (2.0f * fy));
    const float itz = 1.0f / tz;
    const float txz = t0 * itz, tyz = t1 * itz;
    const float txc = fminf(fmaxf(txz, -limx), limx) * tz;
    const float tyc = fminf(fmaxf(tyz, -limy), limy) * tz;
    const float z2 = tz * tz;
    const float J00 = fx * itz, J02 = -fx * txc / z2;
    const float J11 = fy * itz, J12 = -fy * tyc / z2;

    // Tm = J @ R  (2x3)
    const float T00 = J00 * R00 + J02 * R20;
    const float T01 = J00 * R01 + J02 * R21;
    const float T02 = J00 * R02 + J02 * R22;
    const float T10 = J11 * R10 + J12 * R20;
    const float T11 = J11 * R11 + J12 * R21;
    const float T12 = J11 * R12 + J12 * R22;

    const float* C = cov + i * 9;
    const float c00 = C[0], c01 = C[1], c02 = C[2];
    const float c10 = C[3], c11 = C[4], c12 = C[5];
    const float c20 = C[6], c21 = C[7], c22 = C[8];

    // M = Tm @ cov  (2x3); c2 = M @ Tm^T (2x2)
    const float M00 = T00 * c00 + T01 * c10 + T02 * c20;
    const float M01 = T00 * c01 + T01 * c11 + T02 * c21;
    const float M02 = T00 * c02 + T01 * c12 + T02 * c22;
    const float M10 = T10 * c00 + T11 * c10 + T12 * c20;
    const float M11 = T10 * c01 + T11 * c11 + T12 * c21;
    const float M12 = T10 * c02 + T11 * c12 + T12 * c22;

    const float A2 = M00 * T00 + M01 * T01 + M02 * T02 + 0.3f;
    const float B2 = M00 * T10 + M01 * T11 + M02 * T12;
    const float C2 = M10 * T10 + M11 * T11 + M12 * T12 + 0.3f;

    const float det = A2 * C2 - B2 * B2;
    const float inv = 1.0f / det;
    const float cA = C2 * inv, cB = -B2 * inv, cC = A2 * inv;

    const float ux = fx * txz + px - 0.5f;
    const float uy = fy * tyz + py - 0.5f;

    const bool valid = (tz > 0.2f) && (det > 0.0f);
    const float op = valid ? opac[i] : 0.0f;
    // alpha = op*exp(power) >= 1/255  <=>  power >= log(1/(255*op))
    const float pthr = (op > 0.0f) ? logf(1.0f / (255.0f * op)) : 3.0e38f;

    sg[0][i] = ux;
    sg[1][i] = uy;
    sg[2][i] = -0.5f * cA;   // hA
    sg[3][i] = -cB;          // hB
    sg[4][i] = -0.5f * cC;   // hC
    sg[5][i] = op;
    sg[6][i] = pthr;
    sg[7][i] = tz;
    skey[i] = tz;
    sidx[i] = i;
    __syncthreads();

    // Bitonic sort (ascending by tz), 1024 elements, 1024 threads.
    for (int k = 2; k <= NG; k <<= 1) {
        for (int j = k >> 1; j > 0; j >>= 1) {
            const int ixj = i ^ j;
            if (ixj > i) {
                const float a = skey[i];
                const float b = skey[ixj];
                const bool up = ((i & k) == 0);
                if (up ? (a > b) : (a < b)) {
                    skey[i] = b; skey[ixj] = a;
                    const int t = sidx[i]; sidx[i] = sidx[ixj]; sidx[ixj] = t;
                }
            }
            __syncthreads();
        }
    }

    const int s = sidx[i];
    g0[i] = make_float4(sg[0][s], sg[1][s], sg[2][s], sg[3][s]);
    g1[i] = make_float4(sg[4][s], sg[5][s], sg[6][s], 0.0f);

    const float* f = feats + s * CF;
    feat_s[i * 4 + 0] = make_float4(f[0],  f[1],  f[2],  f[3]);
    feat_s[i * 4 + 1] = make_float4(f[4],  f[5],  f[6],  f[7]);
    feat_s[i * 4 + 2] = make_float4(f[8],  f[9],  f[10], f[11]);
    feat_s[i * 4 + 3] = make_float4(f[12], f[13], f[14], 1.0f);
}

// ---------------------------------------------------------------------------
// Kernel B: per-pixel front-to-back compositing over sorted gaussians.
// 256 blocks x 256 threads; block = one 16x16 pixel tile.
// ---------------------------------------------------------------------------
extern "C" __global__ __launch_bounds__(256)
void render_kernel(const float4* __restrict__ g0,
                   const float4* __restrict__ g1,
                   const float4* __restrict__ feat_s,
                   float* __restrict__ out0,
                   float* __restrict__ out1)
{
    const int tid = threadIdx.x;
    const int tx = blockIdx.x & 15, ty = blockIdx.x >> 4;
    const int x = tx * 16 + (tid & 15);
    const int y = ty * 16 + (tid >> 4);
    const float xf = (float)x, yf = (float)y;

    float T = 1.0f;
    float acc[16];
#pragma unroll
    for (int c = 0; c < 16; ++c) acc[c] = 0.0f;

    for (int g = 0; g < NG; ++g) {
        const float4 a = g0[g];   // ux, uy, hA, hB
        const float4 b = g1[g];   // hC, op, pthr, -
        const float dx = a.x - xf;
        const float dy = a.y - yf;
        float power = a.z * dx * dx;
        power = fmaf(a.w, dx * dy, power);
        power = fmaf(b.x, dy * dy, power);
        // process only if power <= 0 (ref gate) and alpha >= 1/255 (ref zeroing);
        // NaN power (degenerate det) fails both compares -> skipped, matching ref.
        if (power <= 0.0f && power >= b.z) {
            const float alpha = fminf(0.99f, b.y * __expf(power));
            const float w = T * alpha;
            const float4 f0 = feat_s[(g << 2) + 0];
            const float4 f1 = feat_s[(g << 2) + 1];
            const float4 f2 = feat_s[(g << 2) + 2];
            const float4 f3 = feat_s[(g << 2) + 3];
            acc[0]  = fmaf(w, f0.x, acc[0]);
            acc[1]  = fmaf(w, f0.y, acc[1]);
            acc[2]  = fmaf(w, f0.z, acc[2]);
            acc[3]  = fmaf(w, f0.w, acc[3]);
            acc[4]  = fmaf(w, f1.x, acc[4]);
            acc[5]  = fmaf(w, f1.y, acc[5]);
            acc[6]  = fmaf(w, f1.z, acc[6]);
            acc[7]  = fmaf(w, f1.w, acc[7]);
            acc[8]  = fmaf(w, f2.x, acc[8]);
            acc[9]  = fmaf(w, f2.y, acc[9]);
            acc[10] = fmaf(w, f2.z, acc[10]);
            acc[11] = fmaf(w, f2.w, acc[11]);
            acc[12] = fmaf(w, f3.x, acc[12]);
            acc[13] = fmaf(w, f3.y, acc[13]);
            acc[14] = fmaf(w, f3.z, acc[14]);
            acc[15] = fmaf(w, f3.w, acc[15]);
            T *= (1.0f - alpha);
        }
        // wave-uniform early exit: residual contribution <= T < 1e-4 << 2e-2 tol
        if ((g & 31) == 31) {
            if (__all(T < 1e-4f)) break;
        }
    }

    const int pix = y * WW + x;
#pragma unroll
    for (int c = 0; c < CF; ++c) out0[pix * CF + c] = acc[c];
    out1[pix] = acc[15];
}

extern "C" void kernel_launch(void* const* d_in, const int* in_sizes, int n_in,
                              void* d_out, int out_size, void* d_ws, size_t ws_size,
                              hipStream_t stream) {
    const float* xyz   = (const float*)d_in[0];
    const float* feats = (const float*)d_in[1];
    const float* opac  = (const float*)d_in[2];
    const float* cov   = (const float*)d_in[3];
    const float* Kp    = (const float*)d_in[4];
    const float* Ep    = (const float*)d_in[5];

    float* ws = (float*)d_ws;
    float4* g0     = (float4*)ws;               // NG float4
    float4* g1     = (float4*)(ws + NG * 4);    // NG float4
    float4* feat_s = (float4*)(ws + NG * 8);    // NG*4 float4

    geom_sort_kernel<<<1, NG, 0, stream>>>(xyz, feats, opac, cov, Kp, Ep,
                                           g0, g1, feat_s);

    float* out0 = (float*)d_out;
    float* out1 = out0 + HH * WW * CF;
    render_kernel<<<256, 256, 0, stream>>>(g0, g1, feat_s, out0, out1);
}

// Round 2
// 91.259 us; speedup vs baseline: 2.8793x; 2.8793x over previous
//
#include <hip/hip_runtime.h>
#include <math.h>

#define HH 256
#define WW 256
#define NG 1024
#define CF 15

// ---------------------------------------------------------------------------
// Kernel A: per-gaussian geometry + hybrid bitonic depth sort + sorted SoA.
// One block of 1024 threads (one thread per gaussian).
// ws layout (float4 units):
//   g0[NG]   = {ux, uy, hA, hB}
//   g1[NG]   = {hC, op, pthr, 0}
//   cull[NG] = {ux, uy, bx, by}   (bbox half-extents of the alpha>=1/255 ellipse)
//   feat[NG*4] = 16 channels (15 feats + 1.0)
// ---------------------------------------------------------------------------
extern "C" __global__ __launch_bounds__(1024)
void geom_sort_kernel(const float* __restrict__ xyz,
                      const float* __restrict__ feats,
                      const float* __restrict__ opac,
                      const float* __restrict__ cov,
                      const float* __restrict__ Kp,
                      const float* __restrict__ Ep,
                      float4* __restrict__ g0,
                      float4* __restrict__ g1,
                      float4* __restrict__ cullv,
                      float4* __restrict__ feat_s)
{
    __shared__ float sg[9][NG];               // 36 KB
    __shared__ unsigned long long skey[NG];   // 8 KB

    const int i = threadIdx.x;

    const float fx = Kp[0], px = Kp[2], fy = Kp[4], py = Kp[5];
    const float R00 = Ep[0], R01 = Ep[1], R02 = Ep[2],  tr0 = Ep[3];
    const float R10 = Ep[4], R11 = Ep[5], R12 = Ep[6],  tr1 = Ep[7];
    const float R20 = Ep[8], R21 = Ep[9], R22 = Ep[10], tr2 = Ep[11];

    const float p0 = xyz[i * 3 + 0], p1 = xyz[i * 3 + 1], p2 = xyz[i * 3 + 2];
    const float t0 = R00 * p0 + R01 * p1 + R02 * p2 + tr0;
    const float t1 = R10 * p0 + R11 * p1 + R12 * p2 + tr1;
    const float tz = R20 * p0 + R21 * p1 + R22 * p2 + tr2;

    const float limx = 1.3f * ((float)WW / (2.0f * fx));
    const float limy = 1.3f * ((float)HH / (2.0f * fy));
    const float itz = 1.0f / tz;
    const float txz = t0 * itz, tyz = t1 * itz;
    const float txc = fminf(fmaxf(txz, -limx), limx) * tz;
    const float tyc = fminf(fmaxf(tyz, -limy), limy) * tz;
    const float z2 = tz * tz;
    const float J00 = fx * itz, J02 = -fx * txc / z2;
    const float J11 = fy * itz, J12 = -fy * tyc / z2;

    // Tm = J @ R  (2x3)
    const float T00 = J00 * R00 + J02 * R20;
    const float T01 = J00 * R01 + J02 * R21;
    const float T02 = J00 * R02 + J02 * R22;
    const float T10 = J11 * R10 + J12 * R20;
    const float T11 = J11 * R11 + J12 * R21;
    const float T12 = J11 * R12 + J12 * R22;

    const float* C = cov + i * 9;
    const float c00 = C[0], c01 = C[1], c02 = C[2];
    const float c10 = C[3], c11 = C[4], c12 = C[5];
    const float c20 = C[6], c21 = C[7], c22 = C[8];

    const float M00 = T00 * c00 + T01 * c10 + T02 * c20;
    const float M01 = T00 * c01 + T01 * c11 + T02 * c21;
    const float M02 = T00 * c02 + T01 * c12 + T02 * c22;
    const float M10 = T10 * c00 + T11 * c10 + T12 * c20;
    const float M11 = T10 * c01 + T11 * c11 + T12 * c21;
    const float M12 = T10 * c02 + T11 * c12 + T12 * c22;

    const float A2 = M00 * T00 + M01 * T01 + M02 * T02 + 0.3f;
    const float B2 = M00 * T10 + M01 * T11 + M02 * T12;
    const float C2 = M10 * T10 + M11 * T11 + M12 * T12 + 0.3f;

    const float det = A2 * C2 - B2 * B2;
    const float inv = 1.0f / det;
    const float cA = C2 * inv, cB = -B2 * inv, cC = A2 * inv;

    const float ux = fx * txz + px - 0.5f;
    const float uy = fy * tyz + py - 0.5f;

    const bool valid = (tz > 0.2f) && (det > 0.0f);
    const float op = valid ? opac[i] : 0.0f;
    // alpha = op*exp(power) >= 1/255  <=>  power >= log(1/(255*op))
    const float pthr = (op > 0.0f) ? logf(1.0f / (255.0f * op)) : 3.0e38f;

    // bbox half-extents of ellipse q <= L, q = cA dx^2 + 2 cB dxdy + cC dy^2.
    // (M^-1)_00 = cC/det2 = A2, (M^-1)_11 = C2, with det2 = cA*cC-cB^2 = 1/det.
    float bx = -1.0e30f, by = -1.0e30f;
    if (op > 0.0f) {
        const float L = -2.0f * pthr;      // = 2*log(255*op) > 0 (op >= 0.3)
        bx = sqrtf(L * A2);
        by = sqrtf(L * C2);
    }

    sg[0][i] = ux;
    sg[1][i] = uy;
    sg[2][i] = -0.5f * cA;   // hA
    sg[3][i] = -cB;          // hB
    sg[4][i] = -0.5f * cC;   // hC
    sg[5][i] = op;
    sg[6][i] = pthr;
    sg[7][i] = bx;
    sg[8][i] = by;

    // sortable key: float tz -> ordered u32, low 32 bits = index (stable ties)
    unsigned u = __float_as_uint(tz);
    u = (u & 0x80000000u) ? ~u : (u | 0x80000000u);
    unsigned long long key = ((unsigned long long)u << 32) | (unsigned)i;

    __syncthreads();

    // Hybrid bitonic sort, ascending. Element i lives in thread i.
    // j >= 64: LDS exchange (2 barriers); j < 64: shfl_xor within the wave.
    for (int k = 2; k <= NG; k <<= 1) {
        for (int j = k >> 1; j > 0; j >>= 1) {
            const bool up = ((i & k) == 0);
            const bool lower = ((i & j) == 0);
            unsigned long long part;
            if (j >= 64) {
                skey[i] = key;
                __syncthreads();
                part = skey[i ^ j];
                __syncthreads();
            } else {
                part = __shfl_xor(key, j);
            }
            const bool takeMin = (up == lower);
            const bool partSmaller = (part < key);
            key = (takeMin == partSmaller) ? part : key;
        }
    }

    const int s = (int)(unsigned)(key & 0xffffffffull);

    g0[i]    = make_float4(sg[0][s], sg[1][s], sg[2][s], sg[3][s]);
    g1[i]    = make_float4(sg[4][s], sg[5][s], sg[6][s], 0.0f);
    cullv[i] = make_float4(sg[0][s], sg[1][s], sg[7][s], sg[8][s]);

    const float* f = feats + s * CF;
    feat_s[i * 4 + 0] = make_float4(f[0],  f[1],  f[2],  f[3]);
    feat_s[i * 4 + 1] = make_float4(f[4],  f[5],  f[6],  f[7]);
    feat_s[i * 4 + 2] = make_float4(f[8],  f[9],  f[10], f[11]);
    feat_s[i * 4 + 3] = make_float4(f[12], f[13], f[14], 1.0f);
}

// ---------------------------------------------------------------------------
// Kernel B: tile-culled, LDS-staged front-to-back compositing.
// 256 blocks x 256 threads; block = one 16x16 pixel tile.
// Per chunk of 256 gaussians: bbox-vs-tile test -> ballot compaction
// (order-preserving) -> stage survivors into LDS -> composite from LDS.
// ---------------------------------------------------------------------------
extern "C" __global__ __launch_bounds__(256)
void render_kernel(const float4* __restrict__ g0,
                   const float4* __restrict__ g1,
                   const float4* __restrict__ cullv,
                   const float4* __restrict__ feat_s,
                   float* __restrict__ out0,
                   float* __restrict__ out1)
{
    __shared__ float4 sA[256];        // {ux,uy,hA,hB}
    __shared__ float4 sB[256];        // {hC,op,pthr,-}
    __shared__ float4 sF[256][4];     // 16 channels
    __shared__ int wcnt[4];

    const int tid = threadIdx.x;
    const int tx = blockIdx.x & 15, ty = blockIdx.x >> 4;
    const int x0 = tx * 16, y0 = ty * 16;
    const int x = x0 + (tid & 15);
    const int y = y0 + (tid >> 4);
    const float xf = (float)x, yf = (float)y;
    const float tlx = (float)x0, thx = (float)(x0 + 15);
    const float tly = (float)y0, thy = (float)(y0 + 15);

    float T = 1.0f;
    float acc[16];
#pragma unroll
    for (int c = 0; c < 16; ++c) acc[c] = 0.0f;

    for (int c = 0; c < NG / 256; ++c) {
        // barrier (WAR vs previous chunk's LDS) + block-uniform early exit
        if (__syncthreads_and(T < 1e-4f)) break;

        const int g = c * 256 + tid;
        const float4 cu = cullv[g];   // {ux, uy, bx, by}
        // exact cull: ellipse bbox vs tile; NaN/invalid fails all compares
        const bool hit = (cu.x + cu.z >= tlx) && (cu.x - cu.z <= thx) &&
                         (cu.y + cu.w >= tly) && (cu.y - cu.w <= thy);

        const unsigned long long bal = __ballot(hit);
        const int lane = tid & 63, w = tid >> 6;
        if (lane == 0) wcnt[w] = __popcll(bal);
        __syncthreads();

        int base = 0;
#pragma unroll
        for (int q = 0; q < 4; ++q) base += (q < w) ? wcnt[q] : 0;
        const int cnt = wcnt[0] + wcnt[1] + wcnt[2] + wcnt[3];

        if (hit) {
            const int slot = base + __popcll(bal & ((1ull << lane) - 1ull));
            sA[slot] = g0[g];
            sB[slot] = g1[g];
            sF[slot][0] = feat_s[(g << 2) + 0];
            sF[slot][1] = feat_s[(g << 2) + 1];
            sF[slot][2] = feat_s[(g << 2) + 2];
            sF[slot][3] = feat_s[(g << 2) + 3];
        }
        __syncthreads();

        for (int e = 0; e < cnt; ++e) {
            const float4 a = sA[e];
            const float4 b = sB[e];
            const float dx = a.x - xf;
            const float dy = a.y - yf;
            float power = a.z * dx * dx;
            power = fmaf(a.w, dx * dy, power);
            power = fmaf(b.x, dy * dy, power);
            if (power <= 0.0f && power >= b.z) {
                const float alpha = fminf(0.99f, b.y * __expf(power));
                const float wgt = T * alpha;
                const float4 f0 = sF[e][0];
                const float4 f1 = sF[e][1];
                const float4 f2 = sF[e][2];
                const float4 f3 = sF[e][3];
                acc[0]  = fmaf(wgt, f0.x, acc[0]);
                acc[1]  = fmaf(wgt, f0.y, acc[1]);
                acc[2]  = fmaf(wgt, f0.z, acc[2]);
                acc[3]  = fmaf(wgt, f0.w, acc[3]);
                acc[4]  = fmaf(wgt, f1.x, acc[4]);
                acc[5]  = fmaf(wgt, f1.y, acc[5]);
                acc[6]  = fmaf(wgt, f1.z, acc[6]);
                acc[7]  = fmaf(wgt, f1.w, acc[7]);
                acc[8]  = fmaf(wgt, f2.x, acc[8]);
                acc[9]  = fmaf(wgt, f2.y, acc[9]);
                acc[10] = fmaf(wgt, f2.z, acc[10]);
                acc[11] = fmaf(wgt, f2.w, acc[11]);
                acc[12] = fmaf(wgt, f3.x, acc[12]);
                acc[13] = fmaf(wgt, f3.y, acc[13]);
                acc[14] = fmaf(wgt, f3.z, acc[14]);
                acc[15] = fmaf(wgt, f3.w, acc[15]);
                T *= (1.0f - alpha);
            }
        }
    }

    const int pix = y * WW + x;
#pragma unroll
    for (int c = 0; c < CF; ++c) out0[pix * CF + c] = acc[c];
    out1[pix] = acc[15];
}

extern "C" void kernel_launch(void* const* d_in, const int* in_sizes, int n_in,
                              void* d_out, int out_size, void* d_ws, size_t ws_size,
                              hipStream_t stream) {
    const float* xyz   = (const float*)d_in[0];
    const float* feats = (const float*)d_in[1];
    const float* opac  = (const float*)d_in[2];
    const float* cov   = (const float*)d_in[3];
    const float* Kp    = (const float*)d_in[4];
    const float* Ep    = (const float*)d_in[5];

    float* ws = (float*)d_ws;
    float4* g0     = (float4*)ws;                // NG float4
    float4* g1     = (float4*)(ws + NG * 4);     // NG float4
    float4* cullv  = (float4*)(ws + NG * 8);     // NG float4
    float4* feat_s = (float4*)(ws + NG * 12);    // NG*4 float4

    geom_sort_kernel<<<1, NG, 0, stream>>>(xyz, feats, opac, cov, Kp, Ep,
                                           g0, g1, cullv, feat_s);

    float* out0 = (float*)d_out;
    float* out1 = out0 + HH * WW * CF;
    render_kernel<<<256, 256, 0, stream>>>(g0, g1, cullv, feat_s, out0, out1);
}

// Round 4
// 89.143 us; speedup vs baseline: 2.9476x; 1.0237x over previous
//
#include <hip/hip_runtime.h>
#include <math.h>

#define HH 256
#define WW 256
#define NG 1024
#define CF 15

// Per-gaussian derived geometry (recomputed redundantly per block; ~150 VALU).
struct G {
    float ux, uy, hA, hB, hC, op, pthr, bx, by;
    unsigned kz;   // order-preserving u32 key of depth tz
};

__device__ __forceinline__ G geom(int i,
                                  const float* __restrict__ xyz,
                                  const float* __restrict__ opac,
                                  const float* __restrict__ cov,
                                  const float* __restrict__ s /* sKE[16] */)
{
    const float fx = s[0], fy = s[1], px = s[2], py = s[3];
    const float R00 = s[4],  R01 = s[5],  R02 = s[6];
    const float R10 = s[7],  R11 = s[8],  R12 = s[9];
    const float R20 = s[10], R21 = s[11], R22 = s[12];
    const float tr0 = s[13], tr1 = s[14], tr2 = s[15];

    const float p0 = xyz[i * 3 + 0], p1 = xyz[i * 3 + 1], p2 = xyz[i * 3 + 2];
    const float t0 = R00 * p0 + R01 * p1 + R02 * p2 + tr0;
    const float t1 = R10 * p0 + R11 * p1 + R12 * p2 + tr1;
    const float tz = R20 * p0 + R21 * p1 + R22 * p2 + tr2;

    const float limx = 1.3f * ((float)WW / (2.0f * fx));
    const float limy = 1.3f * ((float)HH / (2.0f * fy));
    const float itz = 1.0f / tz;
    const float txz = t0 * itz, tyz = t1 * itz;
    const float txc = fminf(fmaxf(txz, -limx), limx) * tz;
    const float tyc = fminf(fmaxf(tyz, -limy), limy) * tz;
    const float z2 = tz * tz;
    const float J00 = fx * itz, J02 = -fx * txc / z2;
    const float J11 = fy * itz, J12 = -fy * tyc / z2;

    // Tm = J @ R (2x3)
    const float T00 = J00 * R00 + J02 * R20;
    const float T01 = J00 * R01 + J02 * R21;
    const float T02 = J00 * R02 + J02 * R22;
    const float T10 = J11 * R10 + J12 * R20;
    const float T11 = J11 * R11 + J12 * R21;
    const float T12 = J11 * R12 + J12 * R22;

    const float* C = cov + i * 9;
    const float M00 = T00 * C[0] + T01 * C[3] + T02 * C[6];
    const float M01 = T00 * C[1] + T01 * C[4] + T02 * C[7];
    const float M02 = T00 * C[2] + T01 * C[5] + T02 * C[8];
    const float M10 = T10 * C[0] + T11 * C[3] + T12 * C[6];
    const float M11 = T10 * C[1] + T11 * C[4] + T12 * C[7];
    const float M12 = T10 * C[2] + T11 * C[5] + T12 * C[8];

    const float A2 = M00 * T00 + M01 * T01 + M02 * T02 + 0.3f;
    const float B2 = M00 * T10 + M01 * T11 + M02 * T12;
    const float C2 = M10 * T10 + M11 * T11 + M12 * T12 + 0.3f;

    const float det = A2 * C2 - B2 * B2;
    const float inv = 1.0f / det;
    const float cA = C2 * inv, cB = -B2 * inv, cC = A2 * inv;

    G r;
    r.ux = fx * txz + px - 0.5f;
    r.uy = fy * tyz + py - 0.5f;
    r.hA = -0.5f * cA;
    r.hB = -cB;
    r.hC = -0.5f * cC;

    const bool valid = (tz > 0.2f) && (det > 0.0f);
    r.op = valid ? opac[i] : 0.0f;
    // alpha = op*exp(power) >= 1/255  <=>  power >= log(1/(255*op)) = pthr
    r.pthr = (r.op > 0.0f) ? logf(1.0f / (255.0f * r.op)) : 3.0e38f;

    // exact bbox of the alpha>=1/255 ellipse q<=L: half-extents sqrt(L*A2), sqrt(L*C2)
    if (r.op > 0.0f) {
        const float L = -2.0f * r.pthr;     // = 2*log(255*op) > 0 since op >= 0.3
        r.bx = sqrtf(L * A2);
        r.by = sqrtf(L * C2);
    } else {
        r.bx = -1.0e30f;
        r.by = -1.0e30f;
    }

    unsigned u = __float_as_uint(tz);
    r.kz = (u & 0x80000000u) ? ~u : (u | 0x80000000u);
    return r;
}

// ---------------------------------------------------------------------------
// Single fused kernel: 256 blocks x 256 threads, block = 16x16 pixel tile.
// Per block: cull all 1024 gaussians (exact ellipse-bbox vs tile) -> append
// (depth,idx) keys -> in-LDS bitonic sort (stable, == global argsort order
// restricted to survivors) -> gather survivor data in depth order -> composite.
// ---------------------------------------------------------------------------
__global__ __launch_bounds__(256)
void render_fused(const float* __restrict__ xyz,
                  const float* __restrict__ feats,
                  const float* __restrict__ opac,
                  const float* __restrict__ cov,
                  const float* __restrict__ Kp,
                  const float* __restrict__ Ep,
                  float* __restrict__ out0,
                  float* __restrict__ out1)
{
    __shared__ float sKE[16];
    __shared__ unsigned long long skey[NG];   // 8 KB
    __shared__ float4 sA[256];                // {ux,uy,hA,hB}
    __shared__ float4 sB[256];                // {hC,op,pthr,-}
    __shared__ float4 sF[256][4];             // 16 channels
    __shared__ int wcnt[4];

    const int tid = threadIdx.x;

    if (tid == 0) {
        sKE[0]  = Kp[0]; sKE[1]  = Kp[4]; sKE[2]  = Kp[2]; sKE[3]  = Kp[5];
        sKE[4]  = Ep[0]; sKE[5]  = Ep[1]; sKE[6]  = Ep[2];
        sKE[7]  = Ep[4]; sKE[8]  = Ep[5]; sKE[9]  = Ep[6];
        sKE[10] = Ep[8]; sKE[11] = Ep[9]; sKE[12] = Ep[10];
        sKE[13] = Ep[3]; sKE[14] = Ep[7]; sKE[15] = Ep[11];
    }
    __syncthreads();

    const int tx = blockIdx.x & 15, ty = blockIdx.x >> 4;
    const int x0 = tx * 16, y0 = ty * 16;
    const float xf = (float)(x0 + (tid & 15));
    const float yf = (float)(y0 + (tid >> 4));
    const float tlx = (float)x0, thx = (float)(x0 + 15);
    const float tly = (float)y0, thy = (float)(y0 + 15);

    // ---- cull phase: test all 1024, append survivor keys (order-independent,
    // sorted right after) ----
    int tot = 0;
    for (int c = 0; c < NG / 256; ++c) {
        const int g = c * 256 + tid;
        const G gg = geom(g, xyz, opac, cov, sKE);
        // NaN-safe: invalid gaussians have bx=-1e30 / NaN coords -> miss
        const bool hit = (gg.ux + gg.bx >= tlx) && (gg.ux - gg.bx <= thx) &&
                         (gg.uy + gg.by >= tly) && (gg.uy - gg.by <= thy);

        const unsigned long long bal = __ballot(hit);
        const int lane = tid & 63, w = tid >> 6;
        if (lane == 0) wcnt[w] = __popcll(bal);
        __syncthreads();
        int base = tot;
#pragma unroll
        for (int q = 0; q < 4; ++q) base += (q < w) ? wcnt[q] : 0;
        if (hit) {
            const int slot = base + __popcll(bal & ((1ull << lane) - 1ull));
            skey[slot] = ((unsigned long long)gg.kz << 32) | (unsigned)g;
        }
        tot += wcnt[0] + wcnt[1] + wcnt[2] + wcnt[3];
        __syncthreads();   // WAR on wcnt for next chunk / before sort
    }

    float T = 1.0f;
    float acc[16];
#pragma unroll
    for (int c = 0; c < 16; ++c) acc[c] = 0.0f;

    if (tot > 0) {
        // ---- pad to pow2 and bitonic sort ascending (stable via idx in low bits) ----
        int K = 1;
        while (K < tot) K <<= 1;
        for (int e = tot + tid; e < K; e += 256) skey[e] = ~0ull;
        __syncthreads();

        for (int k = 2; k <= K; k <<= 1) {
            for (int j = k >> 1; j > 0; j >>= 1) {
                for (int e = tid; e < K; e += 256) {
                    const int ixj = e ^ j;
                    if (ixj > e) {
                        const unsigned long long a = skey[e];
                        const unsigned long long b = skey[ixj];
                        const bool up = ((e & k) == 0);
                        if (up ? (a > b) : (a < b)) {
                            skey[e] = b;
                            skey[ixj] = a;
                        }
                    }
                }
                __syncthreads();
            }
        }

        // ---- runs of 256: gather survivor data in depth order, composite ----
        const int nrun = (tot + 255) >> 8;
        for (int run = 0; run < nrun; ++run) {
            const int rbase = run << 8;
            const int s = rbase + tid;
            if (s < tot) {
                const int idx = (int)(unsigned)(skey[s] & 0xffffffffull);
                const G gg = geom(idx, xyz, opac, cov, sKE);
                sA[tid] = make_float4(gg.ux, gg.uy, gg.hA, gg.hB);
                sB[tid] = make_float4(gg.hC, gg.op, gg.pthr, 0.0f);
                const float* f = feats + idx * CF;
                sF[tid][0] = make_float4(f[0],  f[1],  f[2],  f[3]);
                sF[tid][1] = make_float4(f[4],  f[5],  f[6],  f[7]);
                sF[tid][2] = make_float4(f[8],  f[9],  f[10], f[11]);
                sF[tid][3] = make_float4(f[12], f[13], f[14], 1.0f);
            }
            __syncthreads();

            const int cnt = min(256, tot - rbase);
            for (int e = 0; e < cnt; ++e) {
                const float4 a = sA[e];
                const float4 b = sB[e];
                const float dx = a.x - xf;
                const float dy = a.y - yf;
                float power = a.z * dx * dx;
                power = fmaf(a.w, dx * dy, power);
                power = fmaf(b.x, dy * dy, power);
                if (power <= 0.0f && power >= b.z) {
                    const float alpha = fminf(0.99f, b.y * __expf(power));
                    const float wgt = T * alpha;
                    const float4 f0 = sF[e][0];
                    const float4 f1 = sF[e][1];
                    const float4 f2 = sF[e][2];
                    const float4 f3 = sF[e][3];
                    acc[0]  = fmaf(wgt, f0.x, acc[0]);
                    acc[1]  = fmaf(wgt, f0.y, acc[1]);
                    acc[2]  = fmaf(wgt, f0.z, acc[2]);
                    acc[3]  = fmaf(wgt, f0.w, acc[3]);
                    acc[4]  = fmaf(wgt, f1.x, acc[4]);
                    acc[5]  = fmaf(wgt, f1.y, acc[5]);
                    acc[6]  = fmaf(wgt, f1.z, acc[6]);
                    acc[7]  = fmaf(wgt, f1.w, acc[7]);
                    acc[8]  = fmaf(wgt, f2.x, acc[8]);
                    acc[9]  = fmaf(wgt, f2.y, acc[9]);
                    acc[10] = fmaf(wgt, f2.z, acc[10]);
                    acc[11] = fmaf(wgt, f2.w, acc[11]);
                    acc[12] = fmaf(wgt, f3.x, acc[12]);
                    acc[13] = fmaf(wgt, f3.y, acc[13]);
                    acc[14] = fmaf(wgt, f3.z, acc[14]);
                    acc[15] = fmaf(wgt, f3.w, acc[15]);
                    T *= (1.0f - alpha);
                }
                // residual bound T<1e-4 << 2e-2 tolerance
                if ((e & 31) == 31 && __all(T < 1e-4f)) break;
            }
            if (__syncthreads_and(T < 1e-4f)) break;   // also WAR barrier for next run
        }
    }

    const int pix = (y0 + (tid >> 4)) * WW + (x0 + (tid & 15));
#pragma unroll
    for (int c = 0; c < CF; ++c) out0[pix * CF + c] = acc[c];
    out1[pix] = acc[15];
}

extern "C" void kernel_launch(void* const* d_in, const int* in_sizes, int n_in,
                              void* d_out, int out_size, void* d_ws, size_t ws_size,
                              hipStream_t stream) {
    const float* xyz   = (const float*)d_in[0];
    const float* feats = (const float*)d_in[1];
    const float* opac  = (const float*)d_in[2];
    const float* cov   = (const float*)d_in[3];
    const float* Kp    = (const float*)d_in[4];
    const float* Ep    = (const float*)d_in[5];

    float* out0 = (float*)d_out;
    float* out1 = out0 + HH * WW * CF;

    render_fused<<<256, 256, 0, stream>>>(xyz, feats, opac, cov, Kp, Ep,
                                          out0, out1);
}

// Round 5
// 87.921 us; speedup vs baseline: 2.9886x; 1.0139x over previous
//
#include <hip/hip_runtime.h>
#include <math.h>

#define HH 256
#define WW 256
#define NG 1024
#define CF 15

// ---------------------------------------------------------------------------
// Kernel A: per-gaussian geometry -> SoA in d_ws. 8 blocks x 128 threads.
// ws layout: cullv[NG] float4 {ux,uy,bx,by}
//            gA[NG]    float4 {ux,uy,hA,hB}
//            gB[NG]    float4 {hC,op,pthr,0}
//            feat4[NG*4] float4 (16 channels: 15 feats + 1.0)
//            kz[NG]    u32 order-preserving depth key
// ---------------------------------------------------------------------------
__global__ __launch_bounds__(128)
void geom_kernel(const float* __restrict__ xyz,
                 const float* __restrict__ feats,
                 const float* __restrict__ opac,
                 const float* __restrict__ cov,
                 const float* __restrict__ Kp,
                 const float* __restrict__ Ep,
                 float4* __restrict__ cullv,
                 float4* __restrict__ gA,
                 float4* __restrict__ gB,
                 float4* __restrict__ feat4,
                 unsigned* __restrict__ kz)
{
    const int i = blockIdx.x * 128 + threadIdx.x;

    const float fx = Kp[0], px = Kp[2], fy = Kp[4], py = Kp[5];
    const float R00 = Ep[0], R01 = Ep[1], R02 = Ep[2],  tr0 = Ep[3];
    const float R10 = Ep[4], R11 = Ep[5], R12 = Ep[6],  tr1 = Ep[7];
    const float R20 = Ep[8], R21 = Ep[9], R22 = Ep[10], tr2 = Ep[11];

    const float p0 = xyz[i * 3 + 0], p1 = xyz[i * 3 + 1], p2 = xyz[i * 3 + 2];
    const float t0 = R00 * p0 + R01 * p1 + R02 * p2 + tr0;
    const float t1 = R10 * p0 + R11 * p1 + R12 * p2 + tr1;
    const float tz = R20 * p0 + R21 * p1 + R22 * p2 + tr2;

    const float limx = 1.3f * ((float)WW / (2.0f * fx));
    const float limy = 1.3f * ((float)HH / (2.0f * fy));
    const float itz = 1.0f / tz;
    const float txz = t0 * itz, tyz = t1 * itz;
    const float txc = fminf(fmaxf(txz, -limx), limx) * tz;
    const float tyc = fminf(fmaxf(tyz, -limy), limy) * tz;
    const float z2 = tz * tz;
    const float J00 = fx * itz, J02 = -fx * txc / z2;
    const float J11 = fy * itz, J12 = -fy * tyc / z2;

    // Tm = J @ R (2x3)
    const float T00 = J00 * R00 + J02 * R20;
    const float T01 = J00 * R01 + J02 * R21;
    const float T02 = J00 * R02 + J02 * R22;
    const float T10 = J11 * R10 + J12 * R20;
    const float T11 = J11 * R11 + J12 * R21;
    const float T12 = J11 * R12 + J12 * R22;

    const float* C = cov + i * 9;
    const float M00 = T00 * C[0] + T01 * C[3] + T02 * C[6];
    const float M01 = T00 * C[1] + T01 * C[4] + T02 * C[7];
    const float M02 = T00 * C[2] + T01 * C[5] + T02 * C[8];
    const float M10 = T10 * C[0] + T11 * C[3] + T12 * C[6];
    const float M11 = T10 * C[1] + T11 * C[4] + T12 * C[7];
    const float M12 = T10 * C[2] + T11 * C[5] + T12 * C[8];

    const float A2 = M00 * T00 + M01 * T01 + M02 * T02 + 0.3f;
    const float B2 = M00 * T10 + M01 * T11 + M02 * T12;
    const float C2 = M10 * T10 + M11 * T11 + M12 * T12 + 0.3f;

    const float det = A2 * C2 - B2 * B2;
    const float inv = 1.0f / det;
    const float cA = C2 * inv, cB = -B2 * inv, cC = A2 * inv;

    const float ux = fx * txz + px - 0.5f;
    const float uy = fy * tyz + py - 0.5f;

    const bool valid = (tz > 0.2f) && (det > 0.0f);
    const float op = valid ? opac[i] : 0.0f;
    // alpha = op*exp(power) >= 1/255  <=>  power >= log(1/(255*op)) = pthr
    const float pthr = (op > 0.0f) ? logf(1.0f / (255.0f * op)) : 3.0e38f;

    // exact bbox of the alpha>=1/255 ellipse q<=L: half-extents sqrt(L*A2), sqrt(L*C2)
    float bx = -1.0e30f, by = -1.0e30f;
    if (op > 0.0f) {
        const float L = -2.0f * pthr;   // = 2*log(255*op) > 0 since op >= 0.3
        bx = sqrtf(L * A2);
        by = sqrtf(L * C2);
    }

    unsigned u = __float_as_uint(tz);
    u = (u & 0x80000000u) ? ~u : (u | 0x80000000u);

    cullv[i] = make_float4(ux, uy, bx, by);
    gA[i]    = make_float4(ux, uy, -0.5f * cA, -cB);
    gB[i]    = make_float4(-0.5f * cC, op, pthr, 0.0f);
    kz[i]    = u;

    const float* f = feats + i * CF;
    feat4[i * 4 + 0] = make_float4(f[0],  f[1],  f[2],  f[3]);
    feat4[i * 4 + 1] = make_float4(f[4],  f[5],  f[6],  f[7]);
    feat4[i * 4 + 2] = make_float4(f[8],  f[9],  f[10], f[11]);
    feat4[i * 4 + 3] = make_float4(f[12], f[13], f[14], 1.0f);
}

// ---------------------------------------------------------------------------
// Kernel B: 256 blocks x 256 threads, block = 16x16 pixel tile.
// Cull (coalesced float4, single-prefix compaction, 2 barriers) -> per-tile
// stable sort (wave shfl-bitonic if tot<=64, LDS bitonic otherwise) ->
// gather SoA in depth order -> front-to-back composite.
// Per-tile sort by (depth-key, original index) == global stable argsort order
// restricted to survivors; culled gaussians have alpha==0 in the reference so
// they drop out of the cumprod exactly.
// ---------------------------------------------------------------------------
__global__ __launch_bounds__(256)
void render_kernel(const float4* __restrict__ cullv,
                   const float4* __restrict__ gA,
                   const float4* __restrict__ gB,
                   const float4* __restrict__ feat4,
                   const unsigned* __restrict__ kz,
                   float* __restrict__ out0,
                   float* __restrict__ out1)
{
    __shared__ unsigned long long skey[NG];   // 8 KB
    __shared__ float4 sA[256];                // {ux,uy,hA,hB}
    __shared__ float4 sB[256];                // {hC,op,pthr,-}
    __shared__ float4 sF[256][4];             // 16 channels
    __shared__ int wcnt16[16];                // [chunk][wave]

    const int tid = threadIdx.x;
    const int lane = tid & 63, w = tid >> 6;

    const int tx = blockIdx.x & 15, ty = blockIdx.x >> 4;
    const int x0 = tx * 16, y0 = ty * 16;
    const float xf = (float)(x0 + (tid & 15));
    const float yf = (float)(y0 + (tid >> 4));
    const float tlx = (float)x0, thx = (float)(x0 + 15);
    const float tly = (float)y0, thy = (float)(y0 + 15);

    // ---- cull all 1024: 4 ballots, then one prefix (slot order is arbitrary
    // pre-sort, so chunk-major assignment is fine) ----
    unsigned long long bal[4];
    unsigned k32v[4];
    bool hitv[4];
#pragma unroll
    for (int c = 0; c < 4; ++c) {
        const int g = c * 256 + tid;
        const float4 cu = cullv[g];
        k32v[c] = kz[g];
        // NaN-safe: invalid gaussians have bx=-1e30 / NaN coords -> miss
        hitv[c] = (cu.x + cu.z >= tlx) && (cu.x - cu.z <= thx) &&
                  (cu.y + cu.w >= tly) && (cu.y - cu.w <= thy);
        bal[c] = __ballot(hitv[c]);
        if (lane == 0) wcnt16[c * 4 + w] = __popcll(bal[c]);
    }
    __syncthreads();

    int tot = 0;
    int base_c[4];
#pragma unroll
    for (int c = 0; c < 4; ++c) {
        int b = tot;
#pragma unroll
        for (int q = 0; q < 4; ++q) {
            const int v = wcnt16[c * 4 + q];
            if (q < w) b += v;
            tot += v;
        }
        base_c[c] = b;
    }
#pragma unroll
    for (int c = 0; c < 4; ++c) {
        if (hitv[c]) {
            const int slot = base_c[c] + __popcll(bal[c] & ((1ull << lane) - 1ull));
            skey[slot] = ((unsigned long long)k32v[c] << 32) | (unsigned)(c * 256 + tid);
        }
    }
    __syncthreads();

    float T = 1.0f;
    float acc[16];
#pragma unroll
    for (int c = 0; c < 16; ++c) acc[c] = 0.0f;

    if (tot > 0) {
        if (tot <= 64) {
            // ---- wave-redundant shfl bitonic over 64 keys, no LDS stages ----
            unsigned long long key = (lane < tot) ? skey[lane] : ~0ull;
            __syncthreads();   // all reads done before wave 0 overwrites
#pragma unroll
            for (int k = 2; k <= 64; k <<= 1) {
                for (int j = k >> 1; j > 0; j >>= 1) {
                    const unsigned long long part = __shfl_xor(key, j);
                    const bool takeMin = (((lane & k) == 0) == ((lane & j) == 0));
                    const bool partSmaller = (part < key);
                    key = (takeMin == partSmaller) ? part : key;
                }
            }
            if (w == 0) skey[lane] = key;
            __syncthreads();
        } else {
            // ---- general LDS bitonic over next pow2 ----
            int K = 1;
            while (K < tot) K <<= 1;
            for (int e = tot + tid; e < K; e += 256) skey[e] = ~0ull;
            __syncthreads();
            for (int k = 2; k <= K; k <<= 1) {
                for (int j = k >> 1; j > 0; j >>= 1) {
                    for (int e = tid; e < K; e += 256) {
                        const int ixj = e ^ j;
                        if (ixj > e) {
                            const unsigned long long a = skey[e];
                            const unsigned long long b = skey[ixj];
                            const bool up = ((e & k) == 0);
                            if (up ? (a > b) : (a < b)) {
                                skey[e] = b;
                                skey[ixj] = a;
                            }
                        }
                    }
                    __syncthreads();
                }
            }
        }

        // ---- runs of 256: gather SoA in depth order, composite ----
        const int nrun = (tot + 255) >> 8;
        for (int run = 0; run < nrun; ++run) {
            const int rbase = run << 8;
            const int s = rbase + tid;
            if (s < tot) {
                const int idx = (int)(unsigned)(skey[s] & 0xffffffffull);
                sA[tid] = gA[idx];
                sB[tid] = gB[idx];
                sF[tid][0] = feat4[(idx << 2) + 0];
                sF[tid][1] = feat4[(idx << 2) + 1];
                sF[tid][2] = feat4[(idx << 2) + 2];
                sF[tid][3] = feat4[(idx << 2) + 3];
            }
            __syncthreads();

            const int cnt = min(256, tot - rbase);
            for (int e = 0; e < cnt; ++e) {
                const float4 a = sA[e];
                const float4 b = sB[e];
                const float dx = a.x - xf;
                const float dy = a.y - yf;
                float power = a.z * dx * dx;
                power = fmaf(a.w, dx * dy, power);
                power = fmaf(b.x, dy * dy, power);
                // gate == (power<=0 in ref) AND (alpha>=1/255 zeroing in ref)
                if (power <= 0.0f && power >= b.z) {
                    const float alpha = fminf(0.99f, b.y * __expf(power));
                    const float wgt = T * alpha;
                    const float4 f0 = sF[e][0];
                    const float4 f1 = sF[e][1];
                    const float4 f2 = sF[e][2];
                    const float4 f3 = sF[e][3];
                    acc[0]  = fmaf(wgt, f0.x, acc[0]);
                    acc[1]  = fmaf(wgt, f0.y, acc[1]);
                    acc[2]  = fmaf(wgt, f0.z, acc[2]);
                    acc[3]  = fmaf(wgt, f0.w, acc[3]);
                    acc[4]  = fmaf(wgt, f1.x, acc[4]);
                    acc[5]  = fmaf(wgt, f1.y, acc[5]);
                    acc[6]  = fmaf(wgt, f1.z, acc[6]);
                    acc[7]  = fmaf(wgt, f1.w, acc[7]);
                    acc[8]  = fmaf(wgt, f2.x, acc[8]);
                    acc[9]  = fmaf(wgt, f2.y, acc[9]);
                    acc[10] = fmaf(wgt, f2.z, acc[10]);
                    acc[11] = fmaf(wgt, f2.w, acc[11]);
                    acc[12] = fmaf(wgt, f3.x, acc[12]);
                    acc[13] = fmaf(wgt, f3.y, acc[13]);
                    acc[14] = fmaf(wgt, f3.z, acc[14]);
                    acc[15] = fmaf(wgt, f3.w, acc[15]);
                    T *= (1.0f - alpha);
                }
                // residual bound: remaining contribution <= T < 1e-4 << 2e-2 tol
                if ((e & 31) == 31 && __all(T < 1e-4f)) break;
            }
            if (__syncthreads_and(T < 1e-4f)) break;   // also WAR barrier for next run
        }
    }

    const int pix = (y0 + (tid >> 4)) * WW + (x0 + (tid & 15));
#pragma unroll
    for (int c = 0; c < CF; ++c) out0[pix * CF + c] = acc[c];
    out1[pix] = acc[15];
}

extern "C" void kernel_launch(void* const* d_in, const int* in_sizes, int n_in,
                              void* d_out, int out_size, void* d_ws, size_t ws_size,
                              hipStream_t stream) {
    const float* xyz   = (const float*)d_in[0];
    const float* feats = (const float*)d_in[1];
    const float* opac  = (const float*)d_in[2];
    const float* cov   = (const float*)d_in[3];
    const float* Kp    = (const float*)d_in[4];
    const float* Ep    = (const float*)d_in[5];

    float* ws = (float*)d_ws;
    float4*   cullv = (float4*)ws;                     // NG float4
    float4*   gAp   = (float4*)(ws + NG * 4);          // NG float4
    float4*   gBp   = (float4*)(ws + NG * 8);          // NG float4
    float4*   f4    = (float4*)(ws + NG * 12);         // NG*4 float4
    unsigned* kzp   = (unsigned*)(ws + NG * 28);       // NG u32

    geom_kernel<<<8, 128, 0, stream>>>(xyz, feats, opac, cov, Kp, Ep,
                                       cullv, gAp, gBp, f4, kzp);

    float* out0 = (float*)d_out;
    float* out1 = out0 + HH * WW * CF;
    render_kernel<<<256, 256, 0, stream>>>(cullv, gAp, gBp, f4, kzp,
                                           out0, out1);
}

// Round 6
// 85.364 us; speedup vs baseline: 3.0781x; 1.0300x over previous
//
#include <hip/hip_runtime.h>
#include <math.h>

#define HH 256
#define WW 256
#define NG 1024
#define CF 15

// ---------------------------------------------------------------------------
// Kernel A: per-gaussian geometry -> SoA in d_ws. 8 blocks x 128 threads.
// ws layout: rect[NG]  float4 {xlo,xhi,ylo,yhi}  (bbox of alpha>=1/255 ellipse)
//            gA[NG]    float4 {ux,uy,hA,hB}
//            gB[NG]    float4 {hC,op,pthr,0}
//            feat4[NG*4] float4 (16 channels: 15 feats + 1.0)
//            kz[NG]    u32 order-preserving depth key
// ---------------------------------------------------------------------------
__global__ __launch_bounds__(128)
void geom_kernel(const float* __restrict__ xyz,
                 const float* __restrict__ feats,
                 const float* __restrict__ opac,
                 const float* __restrict__ cov,
                 const float* __restrict__ Kp,
                 const float* __restrict__ Ep,
                 float4* __restrict__ rect,
                 float4* __restrict__ gA,
                 float4* __restrict__ gB,
                 float4* __restrict__ feat4,
                 unsigned* __restrict__ kz)
{
    const int i = blockIdx.x * 128 + threadIdx.x;

    const float fx = Kp[0], px = Kp[2], fy = Kp[4], py = Kp[5];
    const float R00 = Ep[0], R01 = Ep[1], R02 = Ep[2],  tr0 = Ep[3];
    const float R10 = Ep[4], R11 = Ep[5], R12 = Ep[6],  tr1 = Ep[7];
    const float R20 = Ep[8], R21 = Ep[9], R22 = Ep[10], tr2 = Ep[11];

    const float p0 = xyz[i * 3 + 0], p1 = xyz[i * 3 + 1], p2 = xyz[i * 3 + 2];
    const float t0 = R00 * p0 + R01 * p1 + R02 * p2 + tr0;
    const float t1 = R10 * p0 + R11 * p1 + R12 * p2 + tr1;
    const float tz = R20 * p0 + R21 * p1 + R22 * p2 + tr2;

    const float limx = 1.3f * ((float)WW / (2.0f * fx));
    const float limy = 1.3f * ((float)HH / (2.0f * fy));
    const float itz = 1.0f / tz;
    const float txz = t0 * itz, tyz = t1 * itz;
    const float txc = fminf(fmaxf(txz, -limx), limx) * tz;
    const float tyc = fminf(fmaxf(tyz, -limy), limy) * tz;
    const float z2 = tz * tz;
    const float J00 = fx * itz, J02 = -fx * txc / z2;
    const float J11 = fy * itz, J12 = -fy * tyc / z2;

    // Tm = J @ R (2x3)
    const float T00 = J00 * R00 + J02 * R20;
    const float T01 = J00 * R01 + J02 * R21;
    const float T02 = J00 * R02 + J02 * R22;
    const float T10 = J11 * R10 + J12 * R20;
    const float T11 = J11 * R11 + J12 * R21;
    const float T12 = J11 * R12 + J12 * R22;

    const float* C = cov + i * 9;
    const float M00 = T00 * C[0] + T01 * C[3] + T02 * C[6];
    const float M01 = T00 * C[1] + T01 * C[4] + T02 * C[7];
    const float M02 = T00 * C[2] + T01 * C[5] + T02 * C[8];
    const float M10 = T10 * C[0] + T11 * C[3] + T12 * C[6];
    const float M11 = T10 * C[1] + T11 * C[4] + T12 * C[7];
    const float M12 = T10 * C[2] + T11 * C[5] + T12 * C[8];

    const float A2 = M00 * T00 + M01 * T01 + M02 * T02 + 0.3f;
    const float B2 = M00 * T10 + M01 * T11 + M02 * T12;
    const float C2 = M10 * T10 + M11 * T11 + M12 * T12 + 0.3f;

    const float det = A2 * C2 - B2 * B2;
    const float inv = 1.0f / det;
    const float cA = C2 * inv, cB = -B2 * inv, cC = A2 * inv;

    const float ux = fx * txz + px - 0.5f;
    const float uy = fy * tyz + py - 0.5f;

    const bool valid = (tz > 0.2f) && (det > 0.0f);
    const float op = valid ? opac[i] : 0.0f;
    // alpha = op*exp(power) >= 1/255  <=>  power >= log(1/(255*op)) = pthr
    const float pthr = (op > 0.0f) ? logf(1.0f / (255.0f * op)) : 3.0e38f;

    // exact bbox of the alpha>=1/255 ellipse q<=L: half-extents sqrt(L*A2), sqrt(L*C2)
    float xlo = 3.0e38f, xhi = -3.0e38f, ylo = 3.0e38f, yhi = -3.0e38f;
    if (op > 0.0f) {
        const float L = -2.0f * pthr;   // = 2*log(255*op) > 0 since op >= 0.3
        const float bx = sqrtf(L * A2); // NaN if geometry degenerate -> compares fail -> miss
        const float by = sqrtf(L * C2);
        xlo = ux - bx; xhi = ux + bx;
        ylo = uy - by; yhi = uy + by;
    }

    unsigned u = __float_as_uint(tz);
    u = (u & 0x80000000u) ? ~u : (u | 0x80000000u);

    rect[i] = make_float4(xlo, xhi, ylo, yhi);
    gA[i]   = make_float4(ux, uy, -0.5f * cA, -cB);
    gB[i]   = make_float4(-0.5f * cC, op, pthr, 0.0f);
    kz[i]   = u;

    const float* f = feats + i * CF;
    feat4[i * 4 + 0] = make_float4(f[0],  f[1],  f[2],  f[3]);
    feat4[i * 4 + 1] = make_float4(f[4],  f[5],  f[6],  f[7]);
    feat4[i * 4 + 2] = make_float4(f[8],  f[9],  f[10], f[11]);
    feat4[i * 4 + 3] = make_float4(f[12], f[13], f[14], 1.0f);
}

// ---------------------------------------------------------------------------
// Kernel B: 256 blocks x 256 threads, block = 16x16 pixel tile.
// Cull all 1024 (rect-vs-tile, 4 compares) -> single-prefix compaction that
// ALSO stages survivor payloads into LDS slot-indexed -> per-tile stable sort
// of keys {kz<<20 | gidx<<10 | slot} (1-wave shfl bitonic if tot<=64, 2-wave
// hybrid if <=128 (3 barriers), generic LDS bitonic otherwise) -> composite
// straight from LDS via the slot bits. Per-tile sort order == global stable
// argsort restricted to survivors; culled gaussians have alpha==0 in the
// reference so they drop out of the cumprod exactly.
// ---------------------------------------------------------------------------
__global__ __launch_bounds__(256)
void render_kernel(const float4* __restrict__ rect,
                   const float4* __restrict__ gA,
                   const float4* __restrict__ gB,
                   const float4* __restrict__ feat4,
                   const unsigned* __restrict__ kz,
                   float* __restrict__ out0,
                   float* __restrict__ out1)
{
    __shared__ unsigned long long skey[NG];   // 8 KB
    __shared__ float4 sA[256];                // {ux,uy,hA,hB}
    __shared__ float4 sB[256];                // {hC,op,pthr,-}
    __shared__ float4 sF[256][4];             // 16 channels
    __shared__ int wcnt16[16];                // [chunk][wave]

    const int tid = threadIdx.x;
    const int lane = tid & 63, w = tid >> 6;

    const int tx = blockIdx.x & 15, ty = blockIdx.x >> 4;
    const int x0 = tx * 16, y0 = ty * 16;
    const float xf = (float)(x0 + (tid & 15));
    const float yf = (float)(y0 + (tid >> 4));
    const float tlx = (float)x0, thx = (float)(x0 + 15);
    const float tly = (float)y0, thy = (float)(y0 + 15);

    // ---- cull all 1024: 4 ballots, one barrier, one prefix ----
    unsigned long long bal[4];
    unsigned k32v[4];
    bool hitv[4];
#pragma unroll
    for (int c = 0; c < 4; ++c) {
        const int g = c * 256 + tid;
        const float4 r = rect[g];
        k32v[c] = kz[g];
        // NaN-safe: invalid gaussians have xlo=+3e38 / NaN -> miss
        hitv[c] = (r.y >= tlx) && (r.x <= thx) && (r.w >= tly) && (r.z <= thy);
        bal[c] = __ballot(hitv[c]);
        if (lane == 0) wcnt16[c * 4 + w] = __popcll(bal[c]);
    }
    __syncthreads();

    int tot = 0;
    int base_c[4];
#pragma unroll
    for (int c = 0; c < 4; ++c) {
        int b = tot;
#pragma unroll
        for (int q = 0; q < 4; ++q) {
            const int v = wcnt16[c * 4 + q];
            if (q < w) b += v;
            tot += v;
        }
        base_c[c] = b;
    }

    // ---- write keys + stage payloads slot-indexed (order defined by sort) ----
    const unsigned long long lanemask = (1ull << lane) - 1ull;
#pragma unroll
    for (int c = 0; c < 4; ++c) {
        if (hitv[c]) {
            const int g = c * 256 + tid;
            const int slot = base_c[c] + __popcll(bal[c] & lanemask);
            skey[slot] = ((unsigned long long)k32v[c] << 20) |
                         ((unsigned)g << 10) | (unsigned)slot;
            if (slot < 256) {
                sA[slot] = gA[g];
                sB[slot] = gB[g];
                sF[slot][0] = feat4[(g << 2) + 0];
                sF[slot][1] = feat4[(g << 2) + 1];
                sF[slot][2] = feat4[(g << 2) + 2];
                sF[slot][3] = feat4[(g << 2) + 3];
            }
        }
    }
    __syncthreads();

    float T = 1.0f;
    float acc[16];
#pragma unroll
    for (int c = 0; c < 16; ++c) acc[c] = 0.0f;

    if (tot > 0) {
        if (tot <= 64) {
            // ---- 1-wave shfl bitonic over 64 keys (wave-redundant, no stages in LDS) ----
            unsigned long long key = (lane < tot) ? skey[lane] : ~0ull;
            __syncthreads();   // all reads done before wave 0 overwrites
#pragma unroll
            for (int k = 2; k <= 64; k <<= 1) {
                for (int j = k >> 1; j > 0; j >>= 1) {
                    const unsigned long long part = __shfl_xor(key, j);
                    const bool takeMin = (((lane & k) == 0) == ((lane & j) == 0));
                    key = ((part < key) == takeMin) ? part : key;
                }
            }
            if (w == 0) skey[lane] = key;
            __syncthreads();
        } else if (tot <= 128) {
            // ---- 2-wave hybrid bitonic over 128 keys, 3 barriers total ----
            unsigned long long key = ~0ull;
            const int e = (w << 6) | lane;   // virtual element index for w<2
            if (w < 2) key = (e < tot) ? skey[e] : ~0ull;
            __syncthreads();                 // reads done before any writeback
            if (w < 2) {
                // k = 2..64: wave-local (for k=64 direction differs per wave)
#pragma unroll
                for (int k = 2; k <= 64; k <<= 1) {
                    for (int j = k >> 1; j > 0; j >>= 1) {
                        const unsigned long long part = __shfl_xor(key, j);
                        const bool takeMin = (((e & k) == 0) == ((lane & j) == 0));
                        key = ((part < key) == takeMin) ? part : key;
                    }
                }
                skey[e] = key;               // publish for cross-wave step
            }
            __syncthreads();
            if (w < 2) {
                // k=128, j=64: cross-wave exchange (up=true for all e<128)
                const unsigned long long part = skey[e ^ 64];
                const bool takeMin = (w == 0);
                key = ((part < key) == takeMin) ? part : key;
            }
            __syncthreads();                 // reads done before final writeback
            if (w < 2) {
                // k=128, j=32..1: wave-local, up=true
#pragma unroll
                for (int j = 32; j > 0; j >>= 1) {
                    const unsigned long long part = __shfl_xor(key, j);
                    const bool takeMin = ((lane & j) == 0);
                    key = ((part < key) == takeMin) ? part : key;
                }
                skey[e] = key;
            }
            __syncthreads();
        } else {
            // ---- generic LDS bitonic over next pow2 ----
            int K = 1;
            while (K < tot) K <<= 1;
            for (int e = tot + tid; e < K; e += 256) skey[e] = ~0ull;
            __syncthreads();
            for (int k = 2; k <= K; k <<= 1) {
                for (int j = k >> 1; j > 0; j >>= 1) {
                    for (int e = tid; e < K; e += 256) {
                        const int ixj = e ^ j;
                        if (ixj > e) {
                            const unsigned long long a = skey[e];
                            const unsigned long long b = skey[ixj];
                            const bool up = ((e & k) == 0);
                            if (up ? (a > b) : (a < b)) {
                                skey[e] = b;
                                skey[ixj] = a;
                            }
                        }
                    }
                    __syncthreads();
                }
            }
        }

        if (tot <= 256) {
            // ---- composite straight from staged LDS via slot bits ----
            for (int e = 0; e < tot; ++e) {
                const unsigned long long ks = skey[e];
                const int sl = (int)(ks & 1023ull);
                const float4 a = sA[sl];
                const float4 b = sB[sl];
                const float dx = a.x - xf;
                const float dy = a.y - yf;
                float power = a.z * dx * dx;
                power = fmaf(a.w, dx * dy, power);
                power = fmaf(b.x, dy * dy, power);
                // gate == (power<=0 in ref) AND (alpha>=1/255 zeroing in ref)
                if (power <= 0.0f && power >= b.z) {
                    const float alpha = fminf(0.99f, b.y * __expf(power));
                    const float wgt = T * alpha;
                    const float4 f0 = sF[sl][0];
                    const float4 f1 = sF[sl][1];
                    const float4 f2 = sF[sl][2];
                    const float4 f3 = sF[sl][3];
                    acc[0]  = fmaf(wgt, f0.x, acc[0]);
                    acc[1]  = fmaf(wgt, f0.y, acc[1]);
                    acc[2]  = fmaf(wgt, f0.z, acc[2]);
                    acc[3]  = fmaf(wgt, f0.w, acc[3]);
                    acc[4]  = fmaf(wgt, f1.x, acc[4]);
                    acc[5]  = fmaf(wgt, f1.y, acc[5]);
                    acc[6]  = fmaf(wgt, f1.z, acc[6]);
                    acc[7]  = fmaf(wgt, f1.w, acc[7]);
                    acc[8]  = fmaf(wgt, f2.x, acc[8]);
                    acc[9]  = fmaf(wgt, f2.y, acc[9]);
                    acc[10] = fmaf(wgt, f2.z, acc[10]);
                    acc[11] = fmaf(wgt, f2.w, acc[11]);
                    acc[12] = fmaf(wgt, f3.x, acc[12]);
                    acc[13] = fmaf(wgt, f3.y, acc[13]);
                    acc[14] = fmaf(wgt, f3.z, acc[14]);
                    acc[15] = fmaf(wgt, f3.w, acc[15]);
                    T *= (1.0f - alpha);
                }
                // residual bound: remaining contribution <= T < 1e-4 << 2e-2 tol
                if ((e & 31) == 31 && __all(T < 1e-4f)) break;
            }
        } else {
            // ---- fallback (tot > 256, not expected at this density):
            // gather runs of 256 from global by gidx, then composite ----
            const int nrun = (tot + 255) >> 8;
            for (int run = 0; run < nrun; ++run) {
                const int rbase = run << 8;
                const int s = rbase + tid;
                __syncthreads();   // WAR vs staged data / previous run
                if (s < tot) {
                    const int idx = (int)((skey[s] >> 10) & 1023ull);
                    sA[tid] = gA[idx];
                    sB[tid] = gB[idx];
                    sF[tid][0] = feat4[(idx << 2) + 0];
                    sF[tid][1] = feat4[(idx << 2) + 1];
                    sF[tid][2] = feat4[(idx << 2) + 2];
                    sF[tid][3] = feat4[(idx << 2) + 3];
                }
                __syncthreads();

                const int cnt = min(256, tot - rbase);
                for (int e = 0; e < cnt; ++e) {
                    const float4 a = sA[e];
                    const float4 b = sB[e];
                    const float dx = a.x - xf;
                    const float dy = a.y - yf;
                    float power = a.z * dx * dx;
                    power = fmaf(a.w, dx * dy, power);
                    power = fmaf(b.x, dy * dy, power);
                    if (power <= 0.0f && power >= b.z) {
                        const float alpha = fminf(0.99f, b.y * __expf(power));
                        const float wgt = T * alpha;
                        const float4 f0 = sF[e][0];
                        const float4 f1 = sF[e][1];
                        const float4 f2 = sF[e][2];
                        const float4 f3 = sF[e][3];
                        acc[0]  = fmaf(wgt, f0.x, acc[0]);
                        acc[1]  = fmaf(wgt, f0.y, acc[1]);
                        acc[2]  = fmaf(wgt, f0.z, acc[2]);
                        acc[3]  = fmaf(wgt, f0.w, acc[3]);
                        acc[4]  = fmaf(wgt, f1.x, acc[4]);
                        acc[5]  = fmaf(wgt, f1.y, acc[5]);
                        acc[6]  = fmaf(wgt, f1.z, acc[6]);
                        acc[7]  = fmaf(wgt, f1.w, acc[7]);
                        acc[8]  = fmaf(wgt, f2.x, acc[8]);
                        acc[9]  = fmaf(wgt, f2.y, acc[9]);
                        acc[10] = fmaf(wgt, f2.z, acc[10]);
                        acc[11] = fmaf(wgt, f2.w, acc[11]);
                        acc[12] = fmaf(wgt, f3.x, acc[12]);
                        acc[13] = fmaf(wgt, f3.y, acc[13]);
                        acc[14] = fmaf(wgt, f3.z, acc[14]);
                        acc[15] = fmaf(wgt, f3.w, acc[15]);
                        T *= (1.0f - alpha);
                    }
                    if ((e & 31) == 31 && __all(T < 1e-4f)) break;
                }
                if (__syncthreads_and(T < 1e-4f)) break;
            }
        }
    }

    const int pix = (y0 + (tid >> 4)) * WW + (x0 + (tid & 15));
#pragma unroll
    for (int c = 0; c < CF; ++c) out0[pix * CF + c] = acc[c];
    out1[pix] = acc[15];
}

extern "C" void kernel_launch(void* const* d_in, const int* in_sizes, int n_in,
                              void* d_out, int out_size, void* d_ws, size_t ws_size,
                              hipStream_t stream) {
    const float* xyz   = (const float*)d_in[0];
    const float* feats = (const float*)d_in[1];
    const float* opac  = (const float*)d_in[2];
    const float* cov   = (const float*)d_in[3];
    const float* Kp    = (const float*)d_in[4];
    const float* Ep    = (const float*)d_in[5];

    float* ws = (float*)d_ws;
    float4*   rectp = (float4*)ws;                     // NG float4
    float4*   gAp   = (float4*)(ws + NG * 4);          // NG float4
    float4*   gBp   = (float4*)(ws + NG * 8);          // NG float4
    float4*   f4    = (float4*)(ws + NG * 12);         // NG*4 float4
    unsigned* kzp   = (unsigned*)(ws + NG * 28);       // NG u32

    geom_kernel<<<8, 128, 0, stream>>>(xyz, feats, opac, cov, Kp, Ep,
                                       rectp, gAp, gBp, f4, kzp);

    float* out0 = (float*)d_out;
    float* out1 = out0 + HH * WW * CF;
    render_kernel<<<256, 256, 0, stream>>>(rectp, gAp, gBp, f4, kzp,
                                           out0, out1);
}